// Round 3
// baseline (1550.856 us; speedup 1.0000x reference)
//
#include <hip/hip_runtime.h>
#include <hip/hip_bf16.h>
#include <cstdint>
#include <cstddef>

typedef __attribute__((ext_vector_type(8))) short bf16x8;
typedef __attribute__((ext_vector_type(4))) float f32x4;

#define PI2F 6.283185307179586f

__device__ __forceinline__ float bf2f(unsigned short u) {
  union { float f; uint32_t i; } x; x.i = ((uint32_t)u) << 16; return x.f;
}
__device__ __forceinline__ unsigned short f2bf(float f) {
  union { float f; uint32_t i; } x; x.f = f;
  uint32_t r = x.i + 0x7FFF + ((x.i >> 16) & 1);
  return (unsigned short)(r >> 16);
}

// ---------------- fp32 -> bf16 weight conversion ----------------
__global__ void cvt_kernel(const float* __restrict__ src, unsigned short* __restrict__ dst, int n4) {
  int i = blockIdx.x * 256 + threadIdx.x;
  if (i < n4) {
    float4 v = reinterpret_cast<const float4*>(src)[i];
    ushort4 o;
    o.x = f2bf(v.x); o.y = f2bf(v.y); o.z = f2bf(v.z); o.w = f2bf(v.w);
    reinterpret_cast<ushort4*>(dst)[i] = o;
  }
}

// ---------------- per-row 128-pt DFT: col[b,h,i] = (1/128) sum_w img*e^{-2pi i w/128}
__global__ void dft_kernel(const float* __restrict__ img, float2* __restrict__ col,
                           float2* __restrict__ tw) {
  __shared__ float row[128];
  __shared__ float2 twl[128];
  const int bh = blockIdx.x;      // b*128 + h
  const int i = threadIdx.x;      // 0..127
  row[i] = img[bh * 128 + i];
  float s, c;
  sincosf(PI2F * (float)i / 128.0f, &s, &c);
  twl[i] = make_float2(c, s);
  __syncthreads();
  if (bh == 0) tw[i] = twl[i];
  float sr = 0.f, si = 0.f;
  for (int w = 0; w < 128; ++w) {
    float v = row[w];
    float2 t = twl[(i * w) & 127];
    sr += v * t.x;
    si -= v * t.y;
  }
  col[bh * 128 + i] = make_float2(sr * (1.0f / 128.0f), si * (1.0f / 128.0f));
}

// ---------------- spectral separation + mask concat -> x0 (B,134,128,128) bf16
__global__ void sep_kernel(const float2* __restrict__ col, const float2* __restrict__ tw,
                           const float* __restrict__ maskE, unsigned short* __restrict__ x0) {
  const int bc = blockIdx.x;      // b*134 + c
  const int h = blockIdx.y;
  const int w = threadIdx.x;      // 0..127
  const int b = bc / 134;
  const int c = bc - b * 134;
  const size_t oidx = (((size_t)bc * 128) + h) * 128 + w;
  float v;
  if (c < 128) {
    float2 cv = col[((b * 128) + h) * 128 + c];
    float2 t = tw[(w * c) & 127];
    v = cv.x * t.x - cv.y * t.y;
  } else {
    v = maskE[(((size_t)(b * 6 + (c - 128)) * 128) + h) * 128 + w];
  }
  x0[oidx] = f2bf(v);
}

// ---------------- implicit-GEMM conv: 4x4 stride2 pad1, bf16 MFMA ----------------
// M=COUT, N=8*HO*WO, K=CIN*16.  Block: 256 thr = 4 waves (2x2), tile 64x64, BK=32.
template<int CIN, int COUT, int HI, int WI, int HO, int WO, bool LRELU>
__global__ __launch_bounds__(256)
void conv_kernel(const unsigned short* __restrict__ X, const unsigned short* __restrict__ Wt,
                 const float* __restrict__ bias, unsigned short* __restrict__ Y) {
  constexpr int KTOT = CIN * 16;
  constexpr int HOWO = HO * WO;
  constexpr int LHW = __builtin_ctz(HOWO);
  constexpr int LWO = __builtin_ctz(WO);
  __shared__ __align__(16) unsigned short As[64][40];  // [m][k] +8 pad
  __shared__ __align__(16) unsigned short Bs[64][40];  // [n][k] +8 pad
  const int tid = threadIdx.x;
  const int lane = tid & 63;
  const int wv = tid >> 6;
  const int wm = wv >> 1, wn = wv & 1;
  const int n0 = blockIdx.x * 64;
  const int m0 = blockIdx.y * 64;
  const int am = tid >> 2, aks = (tid & 3) * 8;
  const int r = lane & 15, g = lane >> 4;

  f32x4 acc[2][2] = {};

  for (int kc = 0; kc < KTOT / 32; ++kc) {
    // --- global loads into regs first ---
    uint4 av = *reinterpret_cast<const uint4*>(Wt + (size_t)(m0 + am) * KTOT + kc * 32 + aks);
    ushort4 bv[2];
    int bnn[2], bsub[2];
#pragma unroll
    for (int gi = 0; gi < 2; ++gi) {
      int gg = tid + gi * 256;
      int nn = gg >> 3, sub = gg & 7, ci = sub >> 2, kh = sub & 3;
      bnn[gi] = nn; bsub[gi] = sub;
      int n = n0 + nn;
      int b = n >> LHW;
      int rem = n & (HOWO - 1);
      int ho = rem >> LWO;
      int wo = rem & (WO - 1);
      int h = 2 * ho - 1 + kh;
      int cig = kc * 2 + ci;
      bool hv = (unsigned)h < (unsigned)HI;
      const unsigned short* src = X + (((size_t)b * CIN + cig) * HI + (hv ? h : 0)) * WI;
      int wb = 2 * wo - 1;
      ushort4 e;
      e.x = (hv && wb >= 0) ? src[wb] : 0;
      e.y = hv ? src[wb + 1] : 0;
      e.z = hv ? src[wb + 2] : 0;
      e.w = (hv && (wb + 3) < WI) ? src[wb + 3] : 0;
      bv[gi] = e;
    }
    __syncthreads();   // previous compute finished reading LDS
    *reinterpret_cast<uint4*>(&As[am][aks]) = av;
#pragma unroll
    for (int gi = 0; gi < 2; ++gi)
      *reinterpret_cast<ushort4*>(&Bs[bnn[gi]][bsub[gi] * 4]) = bv[gi];
    __syncthreads();
    // --- MFMA ---
    const bf16x8 a0 = *reinterpret_cast<const bf16x8*>(&As[wm * 32 + r][g * 8]);
    const bf16x8 a1 = *reinterpret_cast<const bf16x8*>(&As[wm * 32 + 16 + r][g * 8]);
    const bf16x8 b0 = *reinterpret_cast<const bf16x8*>(&Bs[wn * 32 + r][g * 8]);
    const bf16x8 b1 = *reinterpret_cast<const bf16x8*>(&Bs[wn * 32 + 16 + r][g * 8]);
    acc[0][0] = __builtin_amdgcn_mfma_f32_16x16x32_bf16(a0, b0, acc[0][0], 0, 0, 0);
    acc[0][1] = __builtin_amdgcn_mfma_f32_16x16x32_bf16(a0, b1, acc[0][1], 0, 0, 0);
    acc[1][0] = __builtin_amdgcn_mfma_f32_16x16x32_bf16(a1, b0, acc[1][0], 0, 0, 0);
    acc[1][1] = __builtin_amdgcn_mfma_f32_16x16x32_bf16(a1, b1, acc[1][1], 0, 0, 0);
  }

  // --- epilogue: bias (+ optional lrelu), write bf16 ---
#pragma unroll
  for (int ni = 0; ni < 2; ++ni) {
    int n = n0 + wn * 32 + ni * 16 + r;
    int b = n >> LHW;
    int rem = n & (HOWO - 1);
    size_t obase = ((size_t)b * COUT) * HOWO + rem;
#pragma unroll
    for (int mi = 0; mi < 2; ++mi) {
      f32x4 a = acc[mi][ni];
      int mb = m0 + wm * 32 + mi * 16 + g * 4;
#pragma unroll
      for (int q = 0; q < 4; ++q) {
        int m = mb + q;
        float v = a[q] + bias[m];
        if (LRELU) v = v > 0.f ? v : 0.2f * v;
        Y[obase + (size_t)m * HOWO] = f2bf(v);
      }
    }
  }
}

// ---------------- instance norm (affine=False) + leaky relu, in place ----------------
template<int NPIX>
__global__ __launch_bounds__(64)
void inorm_kernel(unsigned short* __restrict__ Y) {
  constexpr int PER = NPIX / 64;
  const int p = blockIdx.x;
  const int lane = threadIdx.x;
  unsigned short* base = Y + (size_t)p * NPIX;
  float v[PER];
  float s1 = 0.f, s2 = 0.f;
#pragma unroll
  for (int j = 0; j < PER; ++j) {
    float x = bf2f(base[lane + j * 64]);
    v[j] = x; s1 += x; s2 += x * x;
  }
#pragma unroll
  for (int off = 32; off > 0; off >>= 1) {
    s1 += __shfl_xor(s1, off);
    s2 += __shfl_xor(s2, off);
  }
  float mean = s1 * (1.0f / NPIX);
  float var = s2 * (1.0f / NPIX) - mean * mean;
  float rstd = rsqrtf(var + 1e-5f);
#pragma unroll
  for (int j = 0; j < PER; ++j) {
    float t = (v[j] - mean) * rstd;
    t = t > 0.f ? t : 0.2f * t;
    base[lane + j * 64] = f2bf(t);
  }
}

// ---------------- avg pool 8x8 -> pooled (8,1024) fp32 ----------------
__global__ __launch_bounds__(64)
void pool_kernel(const unsigned short* __restrict__ X, float* __restrict__ pooled) {
  const int p = blockIdx.x;
  const int lane = threadIdx.x;
  float s = bf2f(X[(size_t)p * 64 + lane]);
#pragma unroll
  for (int off = 32; off > 0; off >>= 1) s += __shfl_xor(s, off);
  if (lane == 0) pooled[p] = s * (1.0f / 64.0f);
}

// ---------------- final linear: out[b,o] = pooled[b,:] . w4[o,:] + b4[o] ----------------
__global__ __launch_bounds__(64)
void fc_kernel(const float* __restrict__ pooled, const float* __restrict__ w4,
               const float* __restrict__ b4, float* __restrict__ out) {
  const int bo = blockIdx.x;          // b*128 + o
  const int b = bo >> 7, o = bo & 127;
  const int lane = threadIdx.x;
  float s = 0.f;
#pragma unroll
  for (int j = 0; j < 16; ++j) {
    int c = lane + j * 64;
    s += pooled[b * 1024 + c] * w4[o * 1024 + c];
  }
#pragma unroll
  for (int off = 32; off > 0; off >>= 1) s += __shfl_xor(s, off);
  if (lane == 0) out[bo] = s + b4[o];
}

extern "C" void kernel_launch(void* const* d_in, const int* in_sizes, int n_in,
                              void* d_out, int out_size, void* d_ws, size_t ws_size,
                              hipStream_t stream) {
  (void)in_sizes; (void)n_in; (void)out_size; (void)ws_size;
  const float* image = (const float*)d_in[0];
  const float* maskE = (const float*)d_in[1];
  const float* w0 = (const float*)d_in[2];
  const float* b0 = (const float*)d_in[3];
  const float* w1 = (const float*)d_in[4];
  const float* b1 = (const float*)d_in[5];
  const float* w2 = (const float*)d_in[6];
  const float* b2 = (const float*)d_in[7];
  const float* w3 = (const float*)d_in[8];
  const float* b3 = (const float*)d_in[9];
  const float* w4 = (const float*)d_in[10];
  const float* b4 = (const float*)d_in[11];
  float* out = (float*)d_out;

  char* ws = (char*)d_ws;
  size_t off = 0;
  auto alloc = [&](size_t bytes) -> void* {
    void* p = ws + off;
    off = (off + bytes + 255) & ~(size_t)255;
    return p;
  };

  const size_t NW0 = 548864, NW1 = 2097152, NW2 = 8388608, NW3 = 16777216;

  // One 32 MB weight buffer reused for all four convs (stream-ordered:
  // cvt(w_{i+1}) only starts after conv_i has drained on the same stream).
  unsigned short* wbuf = (unsigned short*)alloc(NW3 * 2);
  // Activation ping-pong: A holds x0 (35.1 MB), y1, y3; B holds x1 (16.8 MB), y2.
  unsigned short* bufA = (unsigned short*)alloc((size_t)17563648 * 2);
  unsigned short* bufB = (unsigned short*)alloc((size_t)8388608 * 2);
  float2* col = (float2*)alloc((size_t)131072 * sizeof(float2));
  float2* tw = (float2*)alloc(128 * sizeof(float2));
  float* pooled = (float*)alloc(8192 * 4);

  unsigned short* x0 = bufA;
  unsigned short* x1 = bufB;
  unsigned short* y1 = bufA;
  unsigned short* y2 = bufB;
  unsigned short* y3 = bufA;

  // spectral map
  dft_kernel<<<1024, 128, 0, stream>>>(image, col, tw);
  sep_kernel<<<dim3(8 * 134, 128), 128, 0, stream>>>(col, tw, maskE, x0);

  // conv stack (convert each weight right before its conv, reusing wbuf)
  cvt_kernel<<<(int)((NW0 / 4 + 255) / 256), 256, 0, stream>>>(w0, wbuf, (int)(NW0 / 4));
  conv_kernel<134, 256, 128, 128, 64, 64, true>
      <<<dim3(512, 4), 256, 0, stream>>>(x0, wbuf, b0, x1);

  cvt_kernel<<<(int)((NW1 / 4 + 255) / 256), 256, 0, stream>>>(w1, wbuf, (int)(NW1 / 4));
  conv_kernel<256, 512, 64, 64, 32, 32, false>
      <<<dim3(128, 8), 256, 0, stream>>>(x1, wbuf, b1, y1);
  inorm_kernel<1024><<<4096, 64, 0, stream>>>(y1);

  cvt_kernel<<<(int)((NW2 / 4 + 255) / 256), 256, 0, stream>>>(w2, wbuf, (int)(NW2 / 4));
  conv_kernel<512, 1024, 32, 32, 16, 16, false>
      <<<dim3(32, 16), 256, 0, stream>>>(y1, wbuf, b2, y2);
  inorm_kernel<256><<<8192, 64, 0, stream>>>(y2);

  cvt_kernel<<<(int)((NW3 / 4 + 255) / 256), 256, 0, stream>>>(w3, wbuf, (int)(NW3 / 4));
  conv_kernel<1024, 1024, 16, 16, 8, 8, false>
      <<<dim3(8, 16), 256, 0, stream>>>(y2, wbuf, b3, y3);
  inorm_kernel<64><<<8192, 64, 0, stream>>>(y3);

  // pool + fc
  pool_kernel<<<8192, 64, 0, stream>>>(y3, pooled);
  fc_kernel<<<1024, 64, 0, stream>>>(pooled, w4, b4, out);
}

// Round 6
// 998.371 us; speedup vs baseline: 1.5534x; 1.5534x over previous
//
#include <hip/hip_runtime.h>
#include <hip/hip_bf16.h>
#include <cstdint>
#include <cstddef>

typedef __attribute__((ext_vector_type(8))) short bf16x8;
typedef __attribute__((ext_vector_type(4))) float f32x4;

#define PI2F 6.283185307179586f

__device__ __forceinline__ float bf2f(unsigned short u) {
  union { float f; uint32_t i; } x; x.i = ((uint32_t)u) << 16; return x.f;
}
__device__ __forceinline__ unsigned short f2bf(float f) {
  union { float f; uint32_t i; } x; x.f = f;
  uint32_t r = x.i + 0x7FFF + ((x.i >> 16) & 1);
  return (unsigned short)(r >> 16);
}

// ---------------- fp32 -> bf16 weight conversion ----------------
__global__ void cvt_kernel(const float* __restrict__ src, unsigned short* __restrict__ dst, int n4) {
  int i = blockIdx.x * 256 + threadIdx.x;
  if (i < n4) {
    float4 v = reinterpret_cast<const float4*>(src)[i];
    ushort4 o;
    o.x = f2bf(v.x); o.y = f2bf(v.y); o.z = f2bf(v.z); o.w = f2bf(v.w);
    reinterpret_cast<ushort4*>(dst)[i] = o;
  }
}

// ---------------- per-row 128-pt DFT: col[b,h,i] = (1/128) sum_w img*e^{-2pi i w/128}
__global__ void dft_kernel(const float* __restrict__ img, float2* __restrict__ col,
                           float2* __restrict__ tw) {
  __shared__ float row[128];
  __shared__ float2 twl[128];
  const int bh = blockIdx.x;      // b*128 + h
  const int i = threadIdx.x;      // 0..127
  row[i] = img[bh * 128 + i];
  float s, c;
  sincosf(PI2F * (float)i / 128.0f, &s, &c);
  twl[i] = make_float2(c, s);
  __syncthreads();
  if (bh == 0) tw[i] = twl[i];
  float sr = 0.f, si = 0.f;
  for (int w = 0; w < 128; ++w) {
    float v = row[w];
    float2 t = twl[(i * w) & 127];
    sr += v * t.x;
    si -= v * t.y;
  }
  col[bh * 128 + i] = make_float2(sr * (1.0f / 128.0f), si * (1.0f / 128.0f));
}

// ---------------- spectral separation + mask concat -> x0 (B,134,128,128) bf16
// grid (8*134, 8), block 256: each block covers 16 h rows, ushort2 writes.
__global__ __launch_bounds__(256)
void sep_kernel(const float2* __restrict__ col, const float2* __restrict__ tw,
                const float* __restrict__ maskE, unsigned short* __restrict__ x0) {
  const int bc = blockIdx.x;
  const int b = bc / 134;
  const int c = bc - b * 134;
  const int t = threadIdx.x;
  const int w2 = (t & 63) * 2;
  const int h0 = blockIdx.y * 16 + (t >> 6) * 4;
  if (c < 128) {
    float2 t0 = tw[(w2 * c) & 127];
    float2 t1 = tw[((w2 + 1) * c) & 127];
#pragma unroll
    for (int j = 0; j < 4; ++j) {
      int h = h0 + j;
      float2 cv = col[((b * 128) + h) * 128 + c];
      ushort2 o;
      o.x = f2bf(cv.x * t0.x - cv.y * t0.y);
      o.y = f2bf(cv.x * t1.x - cv.y * t1.y);
      *reinterpret_cast<ushort2*>(&x0[(((size_t)bc * 128) + h) * 128 + w2]) = o;
    }
  } else {
#pragma unroll
    for (int j = 0; j < 4; ++j) {
      int h = h0 + j;
      const float* m = &maskE[(((size_t)(b * 6 + (c - 128)) * 128) + h) * 128 + w2];
      ushort2 o;
      o.x = f2bf(m[0]);
      o.y = f2bf(m[1]);
      *reinterpret_cast<ushort2*>(&x0[(((size_t)bc * 128) + h) * 128 + w2]) = o;
    }
  }
}

// ---------------- shared conv body: stage tiles, MFMA ----------------
// M=COUT, N=8*HO*WO, K=CIN*16.  Block: 256 thr = 4 waves (2x2), tile 64x64, BK=32.

// conv0 variant: full K, fused bias + lrelu, bf16 out
template<int CIN, int COUT, int HI, int WI, int HO, int WO>
__global__ __launch_bounds__(256)
void conv_kernel(const unsigned short* __restrict__ X, const unsigned short* __restrict__ Wt,
                 const float* __restrict__ bias, unsigned short* __restrict__ Y) {
  constexpr int KTOT = CIN * 16;
  constexpr int HOWO = HO * WO;
  constexpr int LHW = __builtin_ctz(HOWO);
  constexpr int LWO = __builtin_ctz(WO);
  __shared__ __align__(16) unsigned short As[64][40];
  __shared__ __align__(16) unsigned short Bs[64][40];
  const int tid = threadIdx.x;
  const int lane = tid & 63;
  const int wv = tid >> 6;
  const int wm = wv >> 1, wn = wv & 1;
  const int n0 = blockIdx.x * 64;
  const int m0 = blockIdx.y * 64;
  const int am = tid >> 2, aks = (tid & 3) * 8;
  const int r = lane & 15, g = lane >> 4;

  f32x4 acc[2][2] = {};

  for (int kc = 0; kc < KTOT / 32; ++kc) {
    uint4 av = *reinterpret_cast<const uint4*>(Wt + (size_t)(m0 + am) * KTOT + kc * 32 + aks);
    ushort4 bv[2];
    int bnn[2], bsub[2];
#pragma unroll
    for (int gi = 0; gi < 2; ++gi) {
      int gg = tid + gi * 256;
      int nn = gg >> 3, sub = gg & 7, ci = sub >> 2, kh = sub & 3;
      bnn[gi] = nn; bsub[gi] = sub;
      int n = n0 + nn;
      int b = n >> LHW;
      int rem = n & (HOWO - 1);
      int ho = rem >> LWO;
      int wo = rem & (WO - 1);
      int h = 2 * ho - 1 + kh;
      int cig = kc * 2 + ci;
      bool hv = (unsigned)h < (unsigned)HI;
      const unsigned short* src = X + (((size_t)b * CIN + cig) * HI + (hv ? h : 0)) * WI;
      int wb = 2 * wo - 1;
      ushort4 e;
      e.x = (hv && wb >= 0) ? src[wb] : 0;
      e.y = hv ? src[wb + 1] : 0;
      e.z = hv ? src[wb + 2] : 0;
      e.w = (hv && (wb + 3) < WI) ? src[wb + 3] : 0;
      bv[gi] = e;
    }
    __syncthreads();
    *reinterpret_cast<uint4*>(&As[am][aks]) = av;
#pragma unroll
    for (int gi = 0; gi < 2; ++gi)
      *reinterpret_cast<ushort4*>(&Bs[bnn[gi]][bsub[gi] * 4]) = bv[gi];
    __syncthreads();
    const bf16x8 a0 = *reinterpret_cast<const bf16x8*>(&As[wm * 32 + r][g * 8]);
    const bf16x8 a1 = *reinterpret_cast<const bf16x8*>(&As[wm * 32 + 16 + r][g * 8]);
    const bf16x8 b0 = *reinterpret_cast<const bf16x8*>(&Bs[wn * 32 + r][g * 8]);
    const bf16x8 b1 = *reinterpret_cast<const bf16x8*>(&Bs[wn * 32 + 16 + r][g * 8]);
    acc[0][0] = __builtin_amdgcn_mfma_f32_16x16x32_bf16(a0, b0, acc[0][0], 0, 0, 0);
    acc[0][1] = __builtin_amdgcn_mfma_f32_16x16x32_bf16(a0, b1, acc[0][1], 0, 0, 0);
    acc[1][0] = __builtin_amdgcn_mfma_f32_16x16x32_bf16(a1, b0, acc[1][0], 0, 0, 0);
    acc[1][1] = __builtin_amdgcn_mfma_f32_16x16x32_bf16(a1, b1, acc[1][1], 0, 0, 0);
  }

#pragma unroll
  for (int ni = 0; ni < 2; ++ni) {
    int n = n0 + wn * 32 + ni * 16 + r;
    int b = n >> LHW;
    int rem = n & (HOWO - 1);
    size_t obase = ((size_t)b * COUT) * HOWO + rem;
#pragma unroll
    for (int mi = 0; mi < 2; ++mi) {
      f32x4 a = acc[mi][ni];
      int mb = m0 + wm * 32 + mi * 16 + g * 4;
#pragma unroll
      for (int q = 0; q < 4; ++q) {
        int m = mb + q;
        float v = a[q] + bias[m];
        v = v > 0.f ? v : 0.2f * v;
        Y[obase + (size_t)m * HOWO] = f2bf(v);
      }
    }
  }
}

// split-K variant: blockIdx.z = k-chunk, fp32 partial out, no bias (cancels in inorm)
template<int CIN, int COUT, int HI, int WI, int HO, int WO, int NSPLIT>
__global__ __launch_bounds__(256)
void conv_split_kernel(const unsigned short* __restrict__ X, const unsigned short* __restrict__ Wt,
                       float* __restrict__ P) {
  constexpr int KTOT = CIN * 16;
  constexpr int HOWO = HO * WO;
  constexpr int LHW = __builtin_ctz(HOWO);
  constexpr int LWO = __builtin_ctz(WO);
  constexpr int KCP = KTOT / 32 / NSPLIT;
  constexpr size_t PSTRIDE = (size_t)8 * COUT * HOWO;
  __shared__ __align__(16) unsigned short As[64][40];
  __shared__ __align__(16) unsigned short Bs[64][40];
  const int tid = threadIdx.x;
  const int lane = tid & 63;
  const int wv = tid >> 6;
  const int wm = wv >> 1, wn = wv & 1;
  const int n0 = blockIdx.x * 64;
  const int m0 = blockIdx.y * 64;
  const int split = blockIdx.z;
  const int am = tid >> 2, aks = (tid & 3) * 8;
  const int r = lane & 15, g = lane >> 4;

  f32x4 acc[2][2] = {};

  for (int kc = split * KCP; kc < (split + 1) * KCP; ++kc) {
    uint4 av = *reinterpret_cast<const uint4*>(Wt + (size_t)(m0 + am) * KTOT + kc * 32 + aks);
    ushort4 bv[2];
    int bnn[2], bsub[2];
#pragma unroll
    for (int gi = 0; gi < 2; ++gi) {
      int gg = tid + gi * 256;
      int nn = gg >> 3, sub = gg & 7, ci = sub >> 2, kh = sub & 3;
      bnn[gi] = nn; bsub[gi] = sub;
      int n = n0 + nn;
      int b = n >> LHW;
      int rem = n & (HOWO - 1);
      int ho = rem >> LWO;
      int wo = rem & (WO - 1);
      int h = 2 * ho - 1 + kh;
      int cig = kc * 2 + ci;
      bool hv = (unsigned)h < (unsigned)HI;
      const unsigned short* src = X + (((size_t)b * CIN + cig) * HI + (hv ? h : 0)) * WI;
      int wb = 2 * wo - 1;
      ushort4 e;
      e.x = (hv && wb >= 0) ? src[wb] : 0;
      e.y = hv ? src[wb + 1] : 0;
      e.z = hv ? src[wb + 2] : 0;
      e.w = (hv && (wb + 3) < WI) ? src[wb + 3] : 0;
      bv[gi] = e;
    }
    __syncthreads();
    *reinterpret_cast<uint4*>(&As[am][aks]) = av;
#pragma unroll
    for (int gi = 0; gi < 2; ++gi)
      *reinterpret_cast<ushort4*>(&Bs[bnn[gi]][bsub[gi] * 4]) = bv[gi];
    __syncthreads();
    const bf16x8 a0 = *reinterpret_cast<const bf16x8*>(&As[wm * 32 + r][g * 8]);
    const bf16x8 a1 = *reinterpret_cast<const bf16x8*>(&As[wm * 32 + 16 + r][g * 8]);
    const bf16x8 b0 = *reinterpret_cast<const bf16x8*>(&Bs[wn * 32 + r][g * 8]);
    const bf16x8 b1 = *reinterpret_cast<const bf16x8*>(&Bs[wn * 32 + 16 + r][g * 8]);
    acc[0][0] = __builtin_amdgcn_mfma_f32_16x16x32_bf16(a0, b0, acc[0][0], 0, 0, 0);
    acc[0][1] = __builtin_amdgcn_mfma_f32_16x16x32_bf16(a0, b1, acc[0][1], 0, 0, 0);
    acc[1][0] = __builtin_amdgcn_mfma_f32_16x16x32_bf16(a1, b0, acc[1][0], 0, 0, 0);
    acc[1][1] = __builtin_amdgcn_mfma_f32_16x16x32_bf16(a1, b1, acc[1][1], 0, 0, 0);
  }

  float* Pb = P + split * PSTRIDE;
#pragma unroll
  for (int ni = 0; ni < 2; ++ni) {
    int n = n0 + wn * 32 + ni * 16 + r;
    int b = n >> LHW;
    int rem = n & (HOWO - 1);
    size_t obase = ((size_t)b * COUT) * HOWO + rem;
#pragma unroll
    for (int mi = 0; mi < 2; ++mi) {
      f32x4 a = acc[mi][ni];
      int mb = m0 + wm * 32 + mi * 16 + g * 4;
#pragma unroll
      for (int q = 0; q < 4; ++q)
        Pb[obase + (size_t)(mb + q) * HOWO] = a[q];
    }
  }
}

// ---------------- fused split-reduce + instance norm + leaky relu -> bf16 ----------------
template<int NPIX, int NSPLIT, int NPLANES>
__global__ __launch_bounds__(64)
void inorm_red_kernel(const float* __restrict__ P, unsigned short* __restrict__ Y) {
  constexpr int PER = NPIX / 64;
  constexpr size_t PSTRIDE = (size_t)NPLANES * NPIX;
  const int p = blockIdx.x;
  const int lane = threadIdx.x;
  const float* base = P + (size_t)p * NPIX;
  float v[PER];
  float s1 = 0.f, s2 = 0.f;
#pragma unroll
  for (int j = 0; j < PER; ++j) {
    float x = 0.f;
#pragma unroll
    for (int s = 0; s < NSPLIT; ++s)
      x += base[s * PSTRIDE + lane + j * 64];
    v[j] = x; s1 += x; s2 += x * x;
  }
#pragma unroll
  for (int off = 32; off > 0; off >>= 1) {
    s1 += __shfl_xor(s1, off);
    s2 += __shfl_xor(s2, off);
  }
  float mean = s1 * (1.0f / NPIX);
  float var = s2 * (1.0f / NPIX) - mean * mean;
  float rstd = rsqrtf(var + 1e-5f);
#pragma unroll
  for (int j = 0; j < PER; ++j) {
    float t = (v[j] - mean) * rstd;
    t = t > 0.f ? t : 0.2f * t;
    Y[(size_t)p * NPIX + lane + j * 64] = f2bf(t);
  }
}

// ---------------- avg pool 8x8 -> pooled (8,1024) fp32 ----------------
__global__ __launch_bounds__(64)
void pool_kernel(const unsigned short* __restrict__ X, float* __restrict__ pooled) {
  const int p = blockIdx.x;
  const int lane = threadIdx.x;
  float s = bf2f(X[(size_t)p * 64 + lane]);
#pragma unroll
  for (int off = 32; off > 0; off >>= 1) s += __shfl_xor(s, off);
  if (lane == 0) pooled[p] = s * (1.0f / 64.0f);
}

// ---------------- final linear ----------------
__global__ __launch_bounds__(64)
void fc_kernel(const float* __restrict__ pooled, const float* __restrict__ w4,
               const float* __restrict__ b4, float* __restrict__ out) {
  const int bo = blockIdx.x;
  const int b = bo >> 7, o = bo & 127;
  const int lane = threadIdx.x;
  float s = 0.f;
#pragma unroll
  for (int j = 0; j < 16; ++j) {
    int c = lane + j * 64;
    s += pooled[b * 1024 + c] * w4[o * 1024 + c];
  }
#pragma unroll
  for (int off = 32; off > 0; off >>= 1) s += __shfl_xor(s, off);
  if (lane == 0) out[bo] = s + b4[o];
}

extern "C" void kernel_launch(void* const* d_in, const int* in_sizes, int n_in,
                              void* d_out, int out_size, void* d_ws, size_t ws_size,
                              hipStream_t stream) {
  (void)in_sizes; (void)n_in; (void)out_size; (void)ws_size;
  const float* image = (const float*)d_in[0];
  const float* maskE = (const float*)d_in[1];
  const float* w0 = (const float*)d_in[2];
  const float* b0 = (const float*)d_in[3];
  const float* w1 = (const float*)d_in[4];
  const float* w2 = (const float*)d_in[6];
  const float* w3 = (const float*)d_in[8];
  const float* w4 = (const float*)d_in[10];
  const float* b4 = (const float*)d_in[11];
  float* out = (float*)d_out;

  char* ws = (char*)d_ws;
  size_t off = 0;
  auto alloc = [&](size_t bytes) -> void* {
    void* p = ws + off;
    off = (off + bytes + 255) & ~(size_t)255;
    return p;
  };

  const size_t NW0 = 548864, NW1 = 2097152, NW2 = 8388608, NW3 = 16777216;

  // wbuf: one 32MB bf16 weight buffer, stream-ordered reuse across convs.
  unsigned short* wbuf = (unsigned short*)alloc(NW3 * 2);
  // bufA: x0 (35.1MB bf16) then fp32 split-partials (max 33.6MB) for convs 1-3.
  char* bufA = (char*)alloc((size_t)17563648 * 2);
  // bufB: x1 (16.8MB) then y1 (8.4MB), y2 (4.2MB), y3 (1MB) bf16.
  char* bufB = (char*)alloc((size_t)8388608 * 2);
  float2* col = (float2*)alloc((size_t)131072 * sizeof(float2));
  float2* tw = (float2*)alloc(128 * sizeof(float2));
  float* pooled = (float*)alloc(8192 * 4);

  unsigned short* x0 = (unsigned short*)bufA;
  float* part = (float*)bufA;
  unsigned short* x1 = (unsigned short*)bufB;
  unsigned short* y1 = (unsigned short*)bufB;
  unsigned short* y2 = (unsigned short*)bufB;
  unsigned short* y3 = (unsigned short*)bufB;

  // spectral map
  dft_kernel<<<1024, 128, 0, stream>>>(image, col, tw);
  sep_kernel<<<dim3(8 * 134, 8), 256, 0, stream>>>(col, tw, maskE, x0);

  // conv0: 134->256, bias+lrelu fused, bf16 out (x0 in bufA -> x1 in bufB)
  cvt_kernel<<<(int)((NW0 / 4 + 255) / 256), 256, 0, stream>>>(w0, wbuf, (int)(NW0 / 4));
  conv_kernel<134, 256, 128, 128, 64, 64>
      <<<dim3(512, 4), 256, 0, stream>>>(x0, wbuf, b0, x1);

  // conv1: 256->512, split-K 2 (x1 in bufB -> partials in bufA -> y1 in bufB)
  cvt_kernel<<<(int)((NW1 / 4 + 255) / 256), 256, 0, stream>>>(w1, wbuf, (int)(NW1 / 4));
  conv_split_kernel<256, 512, 64, 64, 32, 32, 2>
      <<<dim3(128, 8, 2), 256, 0, stream>>>(x1, wbuf, part);
  inorm_red_kernel<1024, 2, 4096><<<4096, 64, 0, stream>>>(part, y1);

  // conv2: 512->1024, split-K 4
  cvt_kernel<<<(int)((NW2 / 4 + 255) / 256), 256, 0, stream>>>(w2, wbuf, (int)(NW2 / 4));
  conv_split_kernel<512, 1024, 32, 32, 16, 16, 4>
      <<<dim3(32, 16, 4), 256, 0, stream>>>(y1, wbuf, part);
  inorm_red_kernel<256, 4, 8192><<<8192, 64, 0, stream>>>(part, y2);

  // conv3: 1024->1024, split-K 16
  cvt_kernel<<<(int)((NW3 / 4 + 255) / 256), 256, 0, stream>>>(w3, wbuf, (int)(NW3 / 4));
  conv_split_kernel<1024, 1024, 16, 16, 8, 8, 16>
      <<<dim3(8, 16, 16), 256, 0, stream>>>(y2, wbuf, part);
  inorm_red_kernel<64, 16, 8192><<<8192, 64, 0, stream>>>(part, y3);

  // pool + fc
  pool_kernel<<<8192, 64, 0, stream>>>(y3, pooled);
  fc_kernel<<<1024, 64, 0, stream>>>(pooled, w4, b4, out);
}

// Round 7
// 514.208 us; speedup vs baseline: 3.0160x; 1.9416x over previous
//
#include <hip/hip_runtime.h>
#include <hip/hip_bf16.h>
#include <cstdint>
#include <cstddef>

typedef __attribute__((ext_vector_type(8))) short bf16x8;
typedef __attribute__((ext_vector_type(4))) float f32x4;

#define PI2F 6.283185307179586f

__device__ __forceinline__ float bf2f(unsigned short u) {
  union { float f; uint32_t i; } x; x.i = ((uint32_t)u) << 16; return x.f;
}
__device__ __forceinline__ unsigned short f2bf(float f) {
  union { float f; uint32_t i; } x; x.f = f;
  uint32_t r = x.i + 0x7FFF + ((x.i >> 16) & 1);
  return (unsigned short)(r >> 16);
}

// ---------------- per-row 128-pt DFT ----------------
__global__ void dft_kernel(const float* __restrict__ img, float2* __restrict__ col,
                           float2* __restrict__ tw) {
  __shared__ float row[128];
  __shared__ float2 twl[128];
  const int bh = blockIdx.x;      // b*128 + h
  const int i = threadIdx.x;      // 0..127
  row[i] = img[bh * 128 + i];
  float s, c;
  sincosf(PI2F * (float)i / 128.0f, &s, &c);
  twl[i] = make_float2(c, s);
  __syncthreads();
  if (bh == 0) tw[i] = twl[i];
  float sr = 0.f, si = 0.f;
  for (int w = 0; w < 128; ++w) {
    float v = row[w];
    float2 t = twl[(i * w) & 127];
    sr += v * t.x;
    si -= v * t.y;
  }
  col[bh * 128 + i] = make_float2(sr * (1.0f / 128.0f), si * (1.0f / 128.0f));
}

// ---------------- spectral sep + mask -> x0 channels-last [8][128][128][144] bf16
// grid (1024) = b*128+h, 256 threads. c: 0..127 spectral, 128..133 mask, 134..143 zero.
__global__ __launch_bounds__(256)
void sep_cl_kernel(const float2* __restrict__ col, const float2* __restrict__ tw,
                   const float* __restrict__ maskE, unsigned short* __restrict__ x0) {
  __shared__ unsigned short lt[128][132];   // [c][w], +4 pad
  __shared__ float2 twl[128];
  const int bh = blockIdx.x;
  const int b = bh >> 7, h = bh & 127;
  const int tid = threadIdx.x;
  if (tid < 128) twl[tid] = tw[tid];
  __syncthreads();
  {
    const int c = tid >> 1;
    const int w0 = (tid & 1) * 64;
    float2 cv = col[(b * 128 + h) * 128 + c];
#pragma unroll 8
    for (int j = 0; j < 64; ++j) {
      int w = w0 + j;
      float2 t = twl[(w * c) & 127];
      lt[c][w] = f2bf(cv.x * t.x - cv.y * t.y);
    }
  }
  __syncthreads();
  if (tid < 144) {
    const int c = tid;
    unsigned short* dst = x0 + ((size_t)bh * 128) * 144 + c;
    if (c < 128) {
      for (int w = 0; w < 128; ++w) dst[(size_t)w * 144] = lt[c][w];
    } else if (c < 134) {
      const float* m = maskE + ((size_t)(b * 6 + (c - 128)) * 128 + h) * 128;
      for (int w = 0; w < 128; ++w) dst[(size_t)w * 144] = f2bf(m[w]);
    } else {
      for (int w = 0; w < 128; ++w) dst[(size_t)w * 144] = 0;
    }
  }
}

// ---------------- weight convert + permute: src[m][ci][t] fp32 -> dst[m][t*CINP+ci] bf16
// grid (ceil(CINP/64), M), 256 threads.
template<int CIN, int CINP>
__global__ __launch_bounds__(256)
void cvtperm_kernel(const float* __restrict__ src, unsigned short* __restrict__ dst) {
  __shared__ unsigned short tile[16][68];
  const int m = blockIdx.y;
  const int ci0 = blockIdx.x * 64;
  const int tid = threadIdx.x;
  {
    const int ci = ci0 + (tid >> 2);
    const int t0 = (tid & 3) * 4;
    float4 v = make_float4(0.f, 0.f, 0.f, 0.f);
    if (ci < CIN) v = *reinterpret_cast<const float4*>(&src[((size_t)m * CIN + ci) * 16 + t0]);
    const int cr = tid >> 2;
    tile[t0 + 0][cr] = f2bf(v.x);
    tile[t0 + 1][cr] = f2bf(v.y);
    tile[t0 + 2][cr] = f2bf(v.z);
    tile[t0 + 3][cr] = f2bf(v.w);
  }
  __syncthreads();
  {
    const int t = tid >> 4;
    const int co = (tid & 15) * 4;
    const int ci = ci0 + co;
    if (ci < CINP) {
      ushort4 o;
      o.x = tile[t][co]; o.y = tile[t][co + 1]; o.z = tile[t][co + 2]; o.w = tile[t][co + 3];
      *reinterpret_cast<ushort4*>(&dst[(size_t)m * (16 * CINP) + (size_t)t * CINP + ci]) = o;
    }
  }
}

// ---------------- channels-last implicit-GEMM conv 4x4 s2 p1, bf16 MFMA -------------
// k = tap*CINP + ci (tap = kh*4+kw). BK=32 = one tap x 32 channels.
// Block: 256 thr = 4 waves (2x2), tile 64x64.

#define CONV_STAGE_AND_MFMA                                                           \
    const int tap = kc / CPT;                                                          \
    const int ci0 = (kc - tap * CPT) * 32;                                             \
    const int kh = tap >> 2, kw = tap & 3;                                             \
    uint4 av = *reinterpret_cast<const uint4*>(Wt + (size_t)(m0 + am) * KTOT + kc * 32 + aks); \
    const int h = 2 * bho - 1 + kh;                                                    \
    const int w = 2 * bwo - 1 + kw;                                                    \
    const int cs = ci0 + csub;                                                         \
    const bool ok = ((unsigned)h < (unsigned)HI) & ((unsigned)w < (unsigned)WI) & (cs < CSTOR); \
    const int hc = ((unsigned)h < (unsigned)HI) ? h : 0;                               \
    const int wc = ((unsigned)w < (unsigned)WI) ? w : 0;                               \
    const int cc = (cs < CSTOR) ? cs : 0;                                              \
    uint4 bvr = *reinterpret_cast<const uint4*>(&X[(((size_t)bb * HI + hc) * WI + wc) * CSTOR + cc]); \
    uint4 zz = make_uint4(0u, 0u, 0u, 0u);                                             \
    uint4 bv = ok ? bvr : zz;                                                          \
    __syncthreads();                                                                   \
    *reinterpret_cast<uint4*>(&As[am][aks]) = av;                                      \
    *reinterpret_cast<uint4*>(&Bs[nn][csub]) = bv;                                     \
    __syncthreads();                                                                   \
    const bf16x8 a0 = *reinterpret_cast<const bf16x8*>(&As[wm * 32 + r][g * 8]);       \
    const bf16x8 a1 = *reinterpret_cast<const bf16x8*>(&As[wm * 32 + 16 + r][g * 8]);  \
    const bf16x8 b0 = *reinterpret_cast<const bf16x8*>(&Bs[wn * 32 + r][g * 8]);       \
    const bf16x8 b1 = *reinterpret_cast<const bf16x8*>(&Bs[wn * 32 + 16 + r][g * 8]);  \
    acc[0][0] = __builtin_amdgcn_mfma_f32_16x16x32_bf16(a0, b0, acc[0][0], 0, 0, 0);   \
    acc[0][1] = __builtin_amdgcn_mfma_f32_16x16x32_bf16(a0, b1, acc[0][1], 0, 0, 0);   \
    acc[1][0] = __builtin_amdgcn_mfma_f32_16x16x32_bf16(a1, b0, acc[1][0], 0, 0, 0);   \
    acc[1][1] = __builtin_amdgcn_mfma_f32_16x16x32_bf16(a1, b1, acc[1][1], 0, 0, 0);

// full-K variant (conv0): fused bias + lrelu, bf16 NHWC out
template<int CINP, int CSTOR, int COUT, int HI, int WI, int HO, int WO>
__global__ __launch_bounds__(256)
void conv_cl_kernel(const unsigned short* __restrict__ X, const unsigned short* __restrict__ Wt,
                    const float* __restrict__ bias, unsigned short* __restrict__ Y) {
  constexpr int KTOT = 16 * CINP;
  constexpr int CPT = CINP / 32;
  constexpr int HOWO = HO * WO;
  constexpr int LHW = __builtin_ctz(HOWO);
  constexpr int LWO = __builtin_ctz(WO);
  __shared__ __align__(16) unsigned short As[64][40];
  __shared__ __align__(16) unsigned short Bs[64][40];
  const int tid = threadIdx.x;
  const int lane = tid & 63;
  const int wv = tid >> 6;
  const int wm = wv >> 1, wn = wv & 1;
  const int n0 = blockIdx.x * 64;
  const int m0 = blockIdx.y * 64;
  const int am = tid >> 2, aks = (tid & 3) * 8;
  const int nn = tid >> 2, csub = (tid & 3) * 8;
  const int r = lane & 15, g = lane >> 4;
  // B-row geometry (fixed per thread)
  const int bn = n0 + nn;
  const int bb = bn >> LHW;
  const int brem = bn & (HOWO - 1);
  const int bho = brem >> LWO;
  const int bwo = brem & (WO - 1);

  f32x4 acc[2][2] = {};

  for (int kc = 0; kc < KTOT / 32; ++kc) {
    CONV_STAGE_AND_MFMA
  }

#pragma unroll
  for (int ni = 0; ni < 2; ++ni) {
    int n = n0 + wn * 32 + ni * 16 + r;
    int b = n >> LHW;
    int rem = n & (HOWO - 1);
    size_t obase = ((size_t)b * HOWO + rem) * COUT;
#pragma unroll
    for (int mi = 0; mi < 2; ++mi) {
      f32x4 a = acc[mi][ni];
      int mb = m0 + wm * 32 + mi * 16 + g * 4;
      ushort4 o;
      float v0 = a[0] + bias[mb + 0]; v0 = v0 > 0.f ? v0 : 0.2f * v0;
      float v1 = a[1] + bias[mb + 1]; v1 = v1 > 0.f ? v1 : 0.2f * v1;
      float v2 = a[2] + bias[mb + 2]; v2 = v2 > 0.f ? v2 : 0.2f * v2;
      float v3 = a[3] + bias[mb + 3]; v3 = v3 > 0.f ? v3 : 0.2f * v3;
      o.x = f2bf(v0); o.y = f2bf(v1); o.z = f2bf(v2); o.w = f2bf(v3);
      *reinterpret_cast<ushort4*>(&Y[obase + mb]) = o;
    }
  }
}

// split-K variant: fp32 NHWC partials, no bias (cancels in inorm)
template<int CINP, int CSTOR, int COUT, int HI, int WI, int HO, int WO, int NSPLIT>
__global__ __launch_bounds__(256)
void conv_cl_split_kernel(const unsigned short* __restrict__ X, const unsigned short* __restrict__ Wt,
                          float* __restrict__ P) {
  constexpr int KTOT = 16 * CINP;
  constexpr int CPT = CINP / 32;
  constexpr int HOWO = HO * WO;
  constexpr int LHW = __builtin_ctz(HOWO);
  constexpr int LWO = __builtin_ctz(WO);
  constexpr int KCP = (KTOT / 32) / NSPLIT;
  constexpr size_t PSTRIDE = (size_t)8 * HOWO * COUT;
  __shared__ __align__(16) unsigned short As[64][40];
  __shared__ __align__(16) unsigned short Bs[64][40];
  const int tid = threadIdx.x;
  const int lane = tid & 63;
  const int wv = tid >> 6;
  const int wm = wv >> 1, wn = wv & 1;
  const int n0 = blockIdx.x * 64;
  const int m0 = blockIdx.y * 64;
  const int split = blockIdx.z;
  const int am = tid >> 2, aks = (tid & 3) * 8;
  const int nn = tid >> 2, csub = (tid & 3) * 8;
  const int r = lane & 15, g = lane >> 4;
  const int bn = n0 + nn;
  const int bb = bn >> LHW;
  const int brem = bn & (HOWO - 1);
  const int bho = brem >> LWO;
  const int bwo = brem & (WO - 1);

  f32x4 acc[2][2] = {};

  for (int kc = split * KCP; kc < (split + 1) * KCP; ++kc) {
    CONV_STAGE_AND_MFMA
  }

  float* Pb = P + split * PSTRIDE;
#pragma unroll
  for (int ni = 0; ni < 2; ++ni) {
    int n = n0 + wn * 32 + ni * 16 + r;
    int b = n >> LHW;
    int rem = n & (HOWO - 1);
    size_t obase = ((size_t)b * HOWO + rem) * COUT;
#pragma unroll
    for (int mi = 0; mi < 2; ++mi) {
      f32x4 a = acc[mi][ni];
      int mb = m0 + wm * 32 + mi * 16 + g * 4;
      *reinterpret_cast<float4*>(&Pb[obase + mb]) = make_float4(a[0], a[1], a[2], a[3]);
    }
  }
}

// ---------------- NHWC split-reduce + instance norm + lrelu -> bf16 ----------------
// grid (COUT/32, 8), 256 thr = 8 hw-slices x 32 channels.
template<int HOWO, int COUT, int NSPLIT>
__global__ __launch_bounds__(256)
void inorm_cl_kernel(const float* __restrict__ P, unsigned short* __restrict__ Y) {
  constexpr size_t PSTRIDE = (size_t)8 * HOWO * COUT;
  const int b = blockIdx.y;
  const int cl = threadIdx.x & 31;
  const int c = blockIdx.x * 32 + cl;
  const int hw0 = threadIdx.x >> 5;   // 0..7
  const float* base = P + ((size_t)b * HOWO) * COUT + c;
  float s1 = 0.f, s2 = 0.f;
  for (int hw = hw0; hw < HOWO; hw += 8) {
    float x = 0.f;
#pragma unroll
    for (int s = 0; s < NSPLIT; ++s) x += base[s * PSTRIDE + (size_t)hw * COUT];
    s1 += x; s2 += x * x;
  }
  __shared__ float r1[8][33], r2[8][33];
  __shared__ float ms[32], rs[32];
  r1[hw0][cl] = s1; r2[hw0][cl] = s2;
  __syncthreads();
  if (threadIdx.x < 32) {
    float a1 = 0.f, a2 = 0.f;
#pragma unroll
    for (int i = 0; i < 8; ++i) { a1 += r1[i][threadIdx.x]; a2 += r2[i][threadIdx.x]; }
    float mean = a1 * (1.0f / HOWO);
    float var = a2 * (1.0f / HOWO) - mean * mean;
    ms[threadIdx.x] = mean;
    rs[threadIdx.x] = rsqrtf(var + 1e-5f);
  }
  __syncthreads();
  const float mean = ms[cl], rstd = rs[cl];
  unsigned short* yb = Y + ((size_t)b * HOWO) * COUT + c;
  for (int hw = hw0; hw < HOWO; hw += 8) {
    float x = 0.f;
#pragma unroll
    for (int s = 0; s < NSPLIT; ++s) x += base[s * PSTRIDE + (size_t)hw * COUT];
    float t = (x - mean) * rstd;
    t = t > 0.f ? t : 0.2f * t;
    yb[(size_t)hw * COUT] = f2bf(t);
  }
}

// ---------------- NHWC avg pool 8x8: [8][64][1024] -> pooled [8][1024] fp32 --------
__global__ __launch_bounds__(256)
void pool_cl_kernel(const unsigned short* __restrict__ X, float* __restrict__ pooled) {
  const int b = blockIdx.x;
  const int c4 = threadIdx.x * 4;
  float4 acc = make_float4(0.f, 0.f, 0.f, 0.f);
  for (int hw = 0; hw < 64; ++hw) {
    ushort4 v = *reinterpret_cast<const ushort4*>(&X[((size_t)b * 64 + hw) * 1024 + c4]);
    acc.x += bf2f(v.x); acc.y += bf2f(v.y); acc.z += bf2f(v.z); acc.w += bf2f(v.w);
  }
  acc.x *= (1.0f / 64.0f); acc.y *= (1.0f / 64.0f);
  acc.z *= (1.0f / 64.0f); acc.w *= (1.0f / 64.0f);
  *reinterpret_cast<float4*>(&pooled[b * 1024 + c4]) = acc;
}

// ---------------- final linear ----------------
__global__ __launch_bounds__(64)
void fc_kernel(const float* __restrict__ pooled, const float* __restrict__ w4,
               const float* __restrict__ b4, float* __restrict__ out) {
  const int bo = blockIdx.x;
  const int b = bo >> 7, o = bo & 127;
  const int lane = threadIdx.x;
  float s = 0.f;
#pragma unroll
  for (int j = 0; j < 16; ++j) {
    int c = lane + j * 64;
    s += pooled[b * 1024 + c] * w4[o * 1024 + c];
  }
#pragma unroll
  for (int off = 32; off > 0; off >>= 1) s += __shfl_xor(s, off);
  if (lane == 0) out[bo] = s + b4[o];
}

extern "C" void kernel_launch(void* const* d_in, const int* in_sizes, int n_in,
                              void* d_out, int out_size, void* d_ws, size_t ws_size,
                              hipStream_t stream) {
  (void)in_sizes; (void)n_in; (void)out_size; (void)ws_size;
  const float* image = (const float*)d_in[0];
  const float* maskE = (const float*)d_in[1];
  const float* w0 = (const float*)d_in[2];
  const float* b0 = (const float*)d_in[3];
  const float* w1 = (const float*)d_in[4];
  const float* w2 = (const float*)d_in[6];
  const float* w3 = (const float*)d_in[8];
  const float* w4 = (const float*)d_in[10];
  const float* b4 = (const float*)d_in[11];
  float* out = (float*)d_out;

  char* ws = (char*)d_ws;
  size_t off = 0;
  auto alloc = [&](size_t bytes) -> void* {
    void* p = ws + off;
    off = (off + bytes + 255) & ~(size_t)255;
    return p;
  };

  // wbuf: one 32MB permuted-weight buffer, stream-ordered reuse.
  unsigned short* wbuf = (unsigned short*)alloc((size_t)1024 * 16384 * 2);
  // bufA: x0cl [8][128][128][144] bf16 (37.75MB), later fp32 split partials (<=33.6MB).
  char* bufA = (char*)alloc((size_t)8 * 128 * 128 * 144 * 2);
  // bufB: NHWC activations a0 (16.8MB) / a1 / a2 / a3, sequential reuse.
  char* bufB = (char*)alloc((size_t)8 * 4096 * 256 * 2);
  float2* col = (float2*)alloc((size_t)131072 * sizeof(float2));
  float2* tw = (float2*)alloc(128 * sizeof(float2));
  float* pooled = (float*)alloc(8192 * 4);

  unsigned short* x0 = (unsigned short*)bufA;
  float* part = (float*)bufA;
  unsigned short* a0 = (unsigned short*)bufB;
  unsigned short* a1 = (unsigned short*)bufB;
  unsigned short* a2 = (unsigned short*)bufB;
  unsigned short* a3 = (unsigned short*)bufB;

  // spectral map (channels-last)
  dft_kernel<<<1024, 128, 0, stream>>>(image, col, tw);
  sep_cl_kernel<<<1024, 256, 0, stream>>>(col, tw, maskE, x0);

  // conv0: 134(pad160)->256, fused bias+lrelu
  cvtperm_kernel<134, 160><<<dim3(3, 256), 256, 0, stream>>>(w0, wbuf);
  conv_cl_kernel<160, 144, 256, 128, 128, 64, 64>
      <<<dim3(512, 4), 256, 0, stream>>>(x0, wbuf, b0, a0);

  // conv1: 256->512, split-K 2
  cvtperm_kernel<256, 256><<<dim3(4, 512), 256, 0, stream>>>(w1, wbuf);
  conv_cl_split_kernel<256, 256, 512, 64, 64, 32, 32, 2>
      <<<dim3(128, 8, 2), 256, 0, stream>>>(a0, wbuf, part);
  inorm_cl_kernel<1024, 512, 2><<<dim3(16, 8), 256, 0, stream>>>(part, a1);

  // conv2: 512->1024, split-K 4
  cvtperm_kernel<512, 512><<<dim3(8, 1024), 256, 0, stream>>>(w2, wbuf);
  conv_cl_split_kernel<512, 512, 1024, 32, 32, 16, 16, 4>
      <<<dim3(32, 16, 4), 256, 0, stream>>>(a1, wbuf, part);
  inorm_cl_kernel<256, 1024, 4><<<dim3(32, 8), 256, 0, stream>>>(part, a2);

  // conv3: 1024->1024, split-K 16
  cvtperm_kernel<1024, 1024><<<dim3(16, 1024), 256, 0, stream>>>(w3, wbuf);
  conv_cl_split_kernel<1024, 1024, 1024, 16, 16, 8, 8, 16>
      <<<dim3(8, 16, 16), 256, 0, stream>>>(a2, wbuf, part);
  inorm_cl_kernel<64, 1024, 16><<<dim3(32, 8), 256, 0, stream>>>(part, a3);

  // pool + fc
  pool_cl_kernel<<<8, 256, 0, stream>>>(a3, pooled);
  fc_kernel<<<1024, 64, 0, stream>>>(pooled, w4, b4, out);
}

// Round 8
// 391.245 us; speedup vs baseline: 3.9639x; 1.3143x over previous
//
#include <hip/hip_runtime.h>
#include <hip/hip_bf16.h>
#include <cstdint>
#include <cstddef>

typedef __attribute__((ext_vector_type(8))) short bf16x8;
typedef __attribute__((ext_vector_type(4))) float f32x4;

#define PI2F 6.283185307179586f

__device__ __forceinline__ float bf2f(unsigned short u) {
  union { float f; uint32_t i; } x; x.i = ((uint32_t)u) << 16; return x.f;
}
__device__ __forceinline__ unsigned short f2bf(float f) {
  union { float f; uint32_t i; } x; x.f = f;
  uint32_t r = x.i + 0x7FFF + ((x.i >> 16) & 1);
  return (unsigned short)(r >> 16);
}

// ---------------- per-row 128-pt DFT ----------------
__global__ void dft_kernel(const float* __restrict__ img, float2* __restrict__ col,
                           float2* __restrict__ tw) {
  __shared__ float row[128];
  __shared__ float2 twl[128];
  const int bh = blockIdx.x;      // b*128 + h
  const int i = threadIdx.x;      // 0..127
  row[i] = img[bh * 128 + i];
  float s, c;
  sincosf(PI2F * (float)i / 128.0f, &s, &c);
  twl[i] = make_float2(c, s);
  __syncthreads();
  if (bh == 0) tw[i] = twl[i];
  float sr = 0.f, si = 0.f;
  for (int w = 0; w < 128; ++w) {
    float v = row[w];
    float2 t = twl[(i * w) & 127];
    sr += v * t.x;
    si -= v * t.y;
  }
  col[bh * 128 + i] = make_float2(sr * (1.0f / 128.0f), si * (1.0f / 128.0f));
}

// ---------------- spectral sep + mask -> x0 channels-last [8][128][128][144] bf16
__global__ __launch_bounds__(256)
void sep_cl_kernel(const float2* __restrict__ col, const float2* __restrict__ tw,
                   const float* __restrict__ maskE, unsigned short* __restrict__ x0) {
  __shared__ unsigned short lt[128][132];   // [c][w], +4 pad
  __shared__ float2 twl[128];
  const int bh = blockIdx.x;
  const int b = bh >> 7, h = bh & 127;
  const int tid = threadIdx.x;
  if (tid < 128) twl[tid] = tw[tid];
  __syncthreads();
  {
    const int c = tid >> 1;
    const int w0 = (tid & 1) * 64;
    float2 cv = col[(b * 128 + h) * 128 + c];
#pragma unroll 8
    for (int j = 0; j < 64; ++j) {
      int w = w0 + j;
      float2 t = twl[(w * c) & 127];
      lt[c][w] = f2bf(cv.x * t.x - cv.y * t.y);
    }
  }
  __syncthreads();
  if (tid < 144) {
    const int c = tid;
    unsigned short* dst = x0 + ((size_t)bh * 128) * 144 + c;
    if (c < 128) {
      for (int w = 0; w < 128; ++w) dst[(size_t)w * 144] = lt[c][w];
    } else if (c < 134) {
      const float* m = maskE + ((size_t)(b * 6 + (c - 128)) * 128 + h) * 128;
      for (int w = 0; w < 128; ++w) dst[(size_t)w * 144] = f2bf(m[w]);
    } else {
      for (int w = 0; w < 128; ++w) dst[(size_t)w * 144] = 0;
    }
  }
}

// ---------------- weight convert + permute: src[m][ci][t] fp32 -> dst[m][t*CINP+ci] bf16
template<int CIN, int CINP>
__global__ __launch_bounds__(256)
void cvtperm_kernel(const float* __restrict__ src, unsigned short* __restrict__ dst) {
  __shared__ unsigned short tile[16][68];
  const int m = blockIdx.y;
  const int ci0 = blockIdx.x * 64;
  const int tid = threadIdx.x;
  {
    const int ci = ci0 + (tid >> 2);
    const int t0 = (tid & 3) * 4;
    float4 v = make_float4(0.f, 0.f, 0.f, 0.f);
    if (ci < CIN) v = *reinterpret_cast<const float4*>(&src[((size_t)m * CIN + ci) * 16 + t0]);
    const int cr = tid >> 2;
    tile[t0 + 0][cr] = f2bf(v.x);
    tile[t0 + 1][cr] = f2bf(v.y);
    tile[t0 + 2][cr] = f2bf(v.z);
    tile[t0 + 3][cr] = f2bf(v.w);
  }
  __syncthreads();
  {
    const int t = tid >> 4;
    const int co = (tid & 15) * 4;
    const int ci = ci0 + co;
    if (ci < CINP) {
      ushort4 o;
      o.x = tile[t][co]; o.y = tile[t][co + 1]; o.z = tile[t][co + 2]; o.w = tile[t][co + 3];
      *reinterpret_cast<ushort4*>(&dst[(size_t)m * (16 * CINP) + (size_t)t * CINP + ci]) = o;
    }
  }
}

// ---------------- channels-last conv 4x4 s2 p1, 128x128 tile, reg-prefetch pipeline --
// k = tap*CINP + ci. Split-K over whole taps (TPS = 16/NSPLIT).
// 256 thr = 4 waves (2x2), wave tile 64x64 (4x4 frags). LDS 128x32 shorts, slot-swizzled.
template<int CINP, int CSTOR, int COUT, int HI, int WI, int HO, int WO, int NSPLIT, bool FUSED>
__global__ __launch_bounds__(256, 2)
void conv_cl2_kernel(const unsigned short* __restrict__ X,
                     const unsigned short* __restrict__ Wt,
                     const float* __restrict__ bias,
                     unsigned short* __restrict__ Y,
                     float* __restrict__ P) {
  constexpr int KTOT = 16 * CINP;
  constexpr int CPT = CINP / 32;          // k-chunks per tap
  constexpr int HOWO = HO * WO;
  constexpr int LHW = __builtin_ctz(HOWO);
  constexpr int LWO = __builtin_ctz(WO);
  constexpr int TPS = 16 / NSPLIT;        // taps per split
  constexpr size_t PSTRIDE = (size_t)8 * HOWO * COUT;

  __shared__ __align__(16) unsigned short As[128 * 32];
  __shared__ __align__(16) unsigned short Bs[128 * 32];

  const int tid = threadIdx.x;
  const int lane = tid & 63;
  const int wv = tid >> 6;
  const int wm = wv >> 1, wn = wv & 1;
  const int n0 = blockIdx.x * 128;
  const int m0 = blockIdx.y * 128;
  const int split = blockIdx.z;
  const int r = lane & 15, g = lane >> 4;

  // staging: each thread handles rows row0 (i=0) and row0+64 (i=1), chunk chk
  const int row0 = tid >> 2;
  const int row1 = row0 + 64;
  const int chk = tid & 3;
  const int lw0 = row0 * 32 + (((chk + ((row0 >> 1) & 3)) & 3) * 8);
  const int lw1 = row1 * 32 + (((chk + ((row1 >> 1) & 3)) & 3) * 8);

  // B-row geometry for my two staging rows
  int bb0, bho0, bwo0, bb1, bho1, bwo1;
  {
    int rn0 = n0 + row0, rn1 = n0 + row1;
    bb0 = rn0 >> LHW; bb1 = rn1 >> LHW;
    int re0 = rn0 & (HOWO - 1), re1 = rn1 & (HOWO - 1);
    bho0 = re0 >> LWO; bho1 = re1 >> LWO;
    bwo0 = re0 & (WO - 1); bwo1 = re1 & (WO - 1);
  }

  const int tap0 = split * TPS;
  int tap = tap0, cc = 0;
  size_t boff0, boff1; bool bok0, bok1;
  auto tap_geom = [&](int t) {
    int kh = t >> 2, kw = t & 3;
    {
      int h = 2 * bho0 - 1 + kh, w = 2 * bwo0 - 1 + kw;
      bool hv = (unsigned)h < (unsigned)HI, wvv = (unsigned)w < (unsigned)WI;
      bok0 = hv && wvv;
      boff0 = (((size_t)bb0 * HI + (hv ? h : 0)) * WI + (wvv ? w : 0)) * (size_t)CSTOR;
    }
    {
      int h = 2 * bho1 - 1 + kh, w = 2 * bwo1 - 1 + kw;
      bool hv = (unsigned)h < (unsigned)HI, wvv = (unsigned)w < (unsigned)WI;
      bok1 = hv && wvv;
      boff1 = (((size_t)bb1 * HI + (hv ? h : 0)) * WI + (wvv ? w : 0)) * (size_t)CSTOR;
    }
  };
  tap_geom(tap);

  uint4 av0, av1, bv0, bv1;
  auto issue = [&](int t, int c) {
    const int kbase = t * CINP + c * 32 + chk * 8;
    av0 = *reinterpret_cast<const uint4*>(Wt + (size_t)(m0 + row0) * KTOT + kbase);
    av1 = *reinterpret_cast<const uint4*>(Wt + (size_t)(m0 + row1) * KTOT + kbase);
    int ci = c * 32 + chk * 8;
    bool ok0 = bok0, ok1 = bok1;
    int cic = ci;
    if constexpr (CSTOR < CINP) {
      if (ci >= CSTOR) { ok0 = false; ok1 = false; cic = 0; }
    }
    uint4 z = make_uint4(0u, 0u, 0u, 0u);
    uint4 v0 = *reinterpret_cast<const uint4*>(X + boff0 + cic);
    uint4 v1 = *reinterpret_cast<const uint4*>(X + boff1 + cic);
    bv0 = ok0 ? v0 : z;
    bv1 = ok1 ? v1 : z;
  };
  issue(tap, 0);

  f32x4 acc[4][4] = {};

  const int NIT = TPS * CPT;
  for (int it = 0; it < NIT; ++it) {
    __syncthreads();                       // prior iter's ds_reads done
    *reinterpret_cast<uint4*>(&As[lw0]) = av0;
    *reinterpret_cast<uint4*>(&As[lw1]) = av1;
    *reinterpret_cast<uint4*>(&Bs[lw0]) = bv0;
    *reinterpret_cast<uint4*>(&Bs[lw1]) = bv1;
    __syncthreads();
    // prefetch next k-chunk (overlaps with ds_read + MFMA below)
    if (it + 1 < NIT) {
      cc++;
      if (cc == CPT) { cc = 0; tap++; tap_geom(tap); }
      issue(tap, cc);
    }
    bf16x8 af[4], bf[4];
#pragma unroll
    for (int mi = 0; mi < 4; ++mi) {
      int rw = wm * 64 + mi * 16 + r;
      af[mi] = *reinterpret_cast<const bf16x8*>(&As[rw * 32 + (((g + ((rw >> 1) & 3)) & 3) * 8)]);
    }
#pragma unroll
    for (int ni = 0; ni < 4; ++ni) {
      int rw = wn * 64 + ni * 16 + r;
      bf[ni] = *reinterpret_cast<const bf16x8*>(&Bs[rw * 32 + (((g + ((rw >> 1) & 3)) & 3) * 8)]);
    }
#pragma unroll
    for (int mi = 0; mi < 4; ++mi)
#pragma unroll
      for (int ni = 0; ni < 4; ++ni)
        acc[mi][ni] = __builtin_amdgcn_mfma_f32_16x16x32_bf16(af[mi], bf[ni], acc[mi][ni], 0, 0, 0);
  }

  // epilogue: C frag mapping col(n)=lane&15=r, row(m)=g*4+q
#pragma unroll
  for (int ni = 0; ni < 4; ++ni) {
    int n = n0 + wn * 64 + ni * 16 + r;
    int b = n >> LHW;
    int rem = n & (HOWO - 1);
    size_t obase = ((size_t)b * HOWO + rem) * COUT;
#pragma unroll
    for (int mi = 0; mi < 4; ++mi) {
      int mb = m0 + wm * 64 + mi * 16 + g * 4;
      f32x4 a = acc[mi][ni];
      if constexpr (FUSED) {
        float v0 = a[0] + bias[mb + 0]; v0 = v0 > 0.f ? v0 : 0.2f * v0;
        float v1 = a[1] + bias[mb + 1]; v1 = v1 > 0.f ? v1 : 0.2f * v1;
        float v2 = a[2] + bias[mb + 2]; v2 = v2 > 0.f ? v2 : 0.2f * v2;
        float v3 = a[3] + bias[mb + 3]; v3 = v3 > 0.f ? v3 : 0.2f * v3;
        ushort4 o;
        o.x = f2bf(v0); o.y = f2bf(v1); o.z = f2bf(v2); o.w = f2bf(v3);
        *reinterpret_cast<ushort4*>(&Y[obase + mb]) = o;
      } else {
        *reinterpret_cast<float4*>(&P[split * PSTRIDE + obase + mb]) =
            make_float4(a[0], a[1], a[2], a[3]);
      }
    }
  }
}

// ---------------- NHWC split-reduce + instance norm + lrelu -> bf16 ----------------
// block: 8 channels x 32 hw-slices. grid (COUT/8, 8).
template<int HOWO, int COUT, int NSPLIT>
__global__ __launch_bounds__(256)
void inorm_cl2_kernel(const float* __restrict__ P, unsigned short* __restrict__ Y) {
  constexpr size_t PSTRIDE = (size_t)8 * HOWO * COUT;
  const int b = blockIdx.y;
  const int cl = threadIdx.x & 7;
  const int c = blockIdx.x * 8 + cl;
  const int hw0 = threadIdx.x >> 3;   // 0..31
  const float* base = P + ((size_t)b * HOWO) * COUT + c;
  float s1 = 0.f, s2 = 0.f;
  for (int hw = hw0; hw < HOWO; hw += 32) {
    float x = 0.f;
#pragma unroll
    for (int s = 0; s < NSPLIT; ++s) x += base[s * PSTRIDE + (size_t)hw * COUT];
    s1 += x; s2 += x * x;
  }
  __shared__ float r1[32][9], r2[32][9];
  __shared__ float ms[8], rs[8];
  r1[hw0][cl] = s1; r2[hw0][cl] = s2;
  __syncthreads();
  if (threadIdx.x < 8) {
    float a1 = 0.f, a2 = 0.f;
#pragma unroll
    for (int i = 0; i < 32; ++i) { a1 += r1[i][threadIdx.x]; a2 += r2[i][threadIdx.x]; }
    float mean = a1 * (1.0f / HOWO);
    float var = a2 * (1.0f / HOWO) - mean * mean;
    ms[threadIdx.x] = mean;
    rs[threadIdx.x] = rsqrtf(var + 1e-5f);
  }
  __syncthreads();
  const float mean = ms[cl], rstd = rs[cl];
  unsigned short* yb = Y + ((size_t)b * HOWO) * COUT + c;
  for (int hw = hw0; hw < HOWO; hw += 32) {
    float x = 0.f;
#pragma unroll
    for (int s = 0; s < NSPLIT; ++s) x += base[s * PSTRIDE + (size_t)hw * COUT];
    float t = (x - mean) * rstd;
    t = t > 0.f ? t : 0.2f * t;
    yb[(size_t)hw * COUT] = f2bf(t);
  }
}

// ---------------- NHWC avg pool 8x8: [8][64][1024] -> pooled [8][1024] fp32 --------
__global__ __launch_bounds__(256)
void pool_cl_kernel(const unsigned short* __restrict__ X, float* __restrict__ pooled) {
  const int b = blockIdx.x;
  const int c4 = threadIdx.x * 4;
  float4 acc = make_float4(0.f, 0.f, 0.f, 0.f);
  for (int hw = 0; hw < 64; ++hw) {
    ushort4 v = *reinterpret_cast<const ushort4*>(&X[((size_t)b * 64 + hw) * 1024 + c4]);
    acc.x += bf2f(v.x); acc.y += bf2f(v.y); acc.z += bf2f(v.z); acc.w += bf2f(v.w);
  }
  acc.x *= (1.0f / 64.0f); acc.y *= (1.0f / 64.0f);
  acc.z *= (1.0f / 64.0f); acc.w *= (1.0f / 64.0f);
  *reinterpret_cast<float4*>(&pooled[b * 1024 + c4]) = acc;
}

// ---------------- final linear ----------------
__global__ __launch_bounds__(64)
void fc_kernel(const float* __restrict__ pooled, const float* __restrict__ w4,
               const float* __restrict__ b4, float* __restrict__ out) {
  const int bo = blockIdx.x;
  const int b = bo >> 7, o = bo & 127;
  const int lane = threadIdx.x;
  float s = 0.f;
#pragma unroll
  for (int j = 0; j < 16; ++j) {
    int c = lane + j * 64;
    s += pooled[b * 1024 + c] * w4[o * 1024 + c];
  }
#pragma unroll
  for (int off = 32; off > 0; off >>= 1) s += __shfl_xor(s, off);
  if (lane == 0) out[bo] = s + b4[o];
}

extern "C" void kernel_launch(void* const* d_in, const int* in_sizes, int n_in,
                              void* d_out, int out_size, void* d_ws, size_t ws_size,
                              hipStream_t stream) {
  (void)in_sizes; (void)n_in; (void)out_size; (void)ws_size;
  const float* image = (const float*)d_in[0];
  const float* maskE = (const float*)d_in[1];
  const float* w0 = (const float*)d_in[2];
  const float* b0 = (const float*)d_in[3];
  const float* w1 = (const float*)d_in[4];
  const float* w2 = (const float*)d_in[6];
  const float* w3 = (const float*)d_in[8];
  const float* w4 = (const float*)d_in[10];
  const float* b4 = (const float*)d_in[11];
  float* out = (float*)d_out;

  char* ws = (char*)d_ws;
  size_t off = 0;
  auto alloc = [&](size_t bytes) -> void* {
    void* p = ws + off;
    off = (off + bytes + 255) & ~(size_t)255;
    return p;
  };

  // wbuf: one 32MB permuted-weight buffer, stream-ordered reuse.
  unsigned short* wbuf = (unsigned short*)alloc((size_t)1024 * 16384 * 2);
  // bufA: x0cl [8][128][128][144] bf16 (37.75MB), later fp32 split partials (<=33.6MB).
  char* bufA = (char*)alloc((size_t)8 * 128 * 128 * 144 * 2);
  // bufB: NHWC activations a0 (16.8MB) / a1 / a2 / a3, sequential reuse.
  char* bufB = (char*)alloc((size_t)8 * 4096 * 256 * 2);
  float2* col = (float2*)alloc((size_t)131072 * sizeof(float2));
  float2* tw = (float2*)alloc(128 * sizeof(float2));
  float* pooled = (float*)alloc(8192 * 4);

  unsigned short* x0 = (unsigned short*)bufA;
  float* part = (float*)bufA;
  unsigned short* a0 = (unsigned short*)bufB;
  unsigned short* a1 = (unsigned short*)bufB;
  unsigned short* a2 = (unsigned short*)bufB;
  unsigned short* a3 = (unsigned short*)bufB;

  // spectral map (channels-last)
  dft_kernel<<<1024, 128, 0, stream>>>(image, col, tw);
  sep_cl_kernel<<<1024, 256, 0, stream>>>(col, tw, maskE, x0);

  // conv0: 134(pad160)->256, fused bias+lrelu, full K
  cvtperm_kernel<134, 160><<<dim3(3, 256), 256, 0, stream>>>(w0, wbuf);
  conv_cl2_kernel<160, 144, 256, 128, 128, 64, 64, 1, true>
      <<<dim3(256, 2, 1), 256, 0, stream>>>(x0, wbuf, b0, a0, nullptr);

  // conv1: 256->512, split-K 2 (8 taps each)
  cvtperm_kernel<256, 256><<<dim3(4, 512), 256, 0, stream>>>(w1, wbuf);
  conv_cl2_kernel<256, 256, 512, 64, 64, 32, 32, 2, false>
      <<<dim3(64, 4, 2), 256, 0, stream>>>(a0, wbuf, nullptr, nullptr, part);
  inorm_cl2_kernel<1024, 512, 2><<<dim3(64, 8), 256, 0, stream>>>(part, a1);

  // conv2: 512->1024, split-K 4 (4 taps each)
  cvtperm_kernel<512, 512><<<dim3(8, 1024), 256, 0, stream>>>(w2, wbuf);
  conv_cl2_kernel<512, 512, 1024, 32, 32, 16, 16, 4, false>
      <<<dim3(16, 8, 4), 256, 0, stream>>>(a1, wbuf, nullptr, nullptr, part);
  inorm_cl2_kernel<256, 1024, 4><<<dim3(128, 8), 256, 0, stream>>>(part, a2);

  // conv3: 1024->1024, split-K 16 (1 tap each)
  cvtperm_kernel<1024, 1024><<<dim3(16, 1024), 256, 0, stream>>>(w3, wbuf);
  conv_cl2_kernel<1024, 1024, 1024, 16, 16, 8, 8, 16, false>
      <<<dim3(4, 8, 16), 256, 0, stream>>>(a2, wbuf, nullptr, nullptr, part);
  inorm_cl2_kernel<64, 1024, 16><<<dim3(128, 8), 256, 0, stream>>>(part, a3);

  // pool + fc
  pool_cl_kernel<<<8, 256, 0, stream>>>(a3, pooled);
  fc_kernel<<<1024, 64, 0, stream>>>(pooled, w4, b4, out);
}

// Round 9
// 316.052 us; speedup vs baseline: 4.9070x; 1.2379x over previous
//
#include <hip/hip_runtime.h>
#include <hip/hip_bf16.h>
#include <cstdint>
#include <cstddef>

typedef __attribute__((ext_vector_type(8))) short bf16x8;
typedef __attribute__((ext_vector_type(4))) float f32x4;

#define PI2F 6.283185307179586f

__device__ __forceinline__ float bf2f(unsigned short u) {
  union { float f; uint32_t i; } x; x.i = ((uint32_t)u) << 16; return x.f;
}
__device__ __forceinline__ unsigned short f2bf(float f) {
  union { float f; uint32_t i; } x; x.f = f;
  uint32_t r = x.i + 0x7FFF + ((x.i >> 16) & 1);
  return (unsigned short)(r >> 16);
}

// ---------------- per-row 128-pt DFT ----------------
__global__ void dft_kernel(const float* __restrict__ img, float2* __restrict__ col,
                           float2* __restrict__ tw) {
  __shared__ float row[128];
  __shared__ float2 twl[128];
  const int bh = blockIdx.x;      // b*128 + h
  const int i = threadIdx.x;      // 0..127
  row[i] = img[bh * 128 + i];
  float s, c;
  sincosf(PI2F * (float)i / 128.0f, &s, &c);
  twl[i] = make_float2(c, s);
  __syncthreads();
  if (bh == 0) tw[i] = twl[i];
  float sr = 0.f, si = 0.f;
  for (int w = 0; w < 128; ++w) {
    float v = row[w];
    float2 t = twl[(i * w) & 127];
    sr += v * t.x;
    si -= v * t.y;
  }
  col[bh * 128 + i] = make_float2(sr * (1.0f / 128.0f), si * (1.0f / 128.0f));
}

// ---------------- spectral sep + mask -> x0 channels-last [8][128][128][144] bf16
__global__ __launch_bounds__(256)
void sep_cl_kernel(const float2* __restrict__ col, const float2* __restrict__ tw,
                   const float* __restrict__ maskE, unsigned short* __restrict__ x0) {
  __shared__ unsigned short lt[128][132];   // [c][w], +4 pad
  __shared__ float2 twl[128];
  const int bh = blockIdx.x;
  const int b = bh >> 7, h = bh & 127;
  const int tid = threadIdx.x;
  if (tid < 128) twl[tid] = tw[tid];
  __syncthreads();
  {
    const int c = tid >> 1;
    const int w0 = (tid & 1) * 64;
    float2 cv = col[(b * 128 + h) * 128 + c];
#pragma unroll 8
    for (int j = 0; j < 64; ++j) {
      int w = w0 + j;
      float2 t = twl[(w * c) & 127];
      lt[c][w] = f2bf(cv.x * t.x - cv.y * t.y);
    }
  }
  __syncthreads();
  if (tid < 144) {
    const int c = tid;
    unsigned short* dst = x0 + ((size_t)bh * 128) * 144 + c;
    if (c < 128) {
      for (int w = 0; w < 128; ++w) dst[(size_t)w * 144] = lt[c][w];
    } else if (c < 134) {
      const float* m = maskE + ((size_t)(b * 6 + (c - 128)) * 128 + h) * 128;
      for (int w = 0; w < 128; ++w) dst[(size_t)w * 144] = f2bf(m[w]);
    } else {
      for (int w = 0; w < 128; ++w) dst[(size_t)w * 144] = 0;
    }
  }
}

// ---------------- weight convert + permute: src[m][ci][t] fp32 -> dst[m][t*CINP+ci] bf16
template<int CIN, int CINP>
__global__ __launch_bounds__(256)
void cvtperm_kernel(const float* __restrict__ src, unsigned short* __restrict__ dst) {
  __shared__ unsigned short tile[16][68];
  const int m = blockIdx.y;
  const int ci0 = blockIdx.x * 64;
  const int tid = threadIdx.x;
  {
    const int ci = ci0 + (tid >> 2);
    const int t0 = (tid & 3) * 4;
    float4 v = make_float4(0.f, 0.f, 0.f, 0.f);
    if (ci < CIN) v = *reinterpret_cast<const float4*>(&src[((size_t)m * CIN + ci) * 16 + t0]);
    const int cr = tid >> 2;
    tile[t0 + 0][cr] = f2bf(v.x);
    tile[t0 + 1][cr] = f2bf(v.y);
    tile[t0 + 2][cr] = f2bf(v.z);
    tile[t0 + 3][cr] = f2bf(v.w);
  }
  __syncthreads();
  {
    const int t = tid >> 4;
    const int co = (tid & 15) * 4;
    const int ci = ci0 + co;
    if (ci < CINP) {
      ushort4 o;
      o.x = tile[t][co]; o.y = tile[t][co + 1]; o.z = tile[t][co + 2]; o.w = tile[t][co + 3];
      *reinterpret_cast<ushort4*>(&dst[(size_t)m * (16 * CINP) + (size_t)t * CINP + ci]) = o;
    }
  }
}

// ---------------- channels-last conv, 128x128 tile, LDS dbuf + depth-2 reg prefetch --
// k = tap*CINP + ci. Split-K over whole taps (TPS = 16/NSPLIT).
// 256 thr = 4 waves (2x2), wave tile 64x64 (4x4 frags). One barrier per 32-k-step.
template<int CINP, int CSTOR, int COUT, int HI, int WI, int HO, int WO, int NSPLIT, bool FUSED>
__global__ __launch_bounds__(256, 2)
void conv_cl3_kernel(const unsigned short* __restrict__ X,
                     const unsigned short* __restrict__ Wt,
                     const float* __restrict__ bias,
                     unsigned short* __restrict__ Y,
                     float* __restrict__ P) {
  constexpr int KTOT = 16 * CINP;
  constexpr int CPT = CINP / 32;          // k-chunks per tap
  constexpr int HOWO = HO * WO;
  constexpr int LHW = __builtin_ctz(HOWO);
  constexpr int LWO = __builtin_ctz(WO);
  constexpr int TPS = 16 / NSPLIT;        // taps per split
  constexpr size_t PSTRIDE = (size_t)8 * HOWO * COUT;
  constexpr int NIT = TPS * CPT;          // always even (80/64/64/32)

  __shared__ __align__(16) unsigned short As[2][128 * 32];
  __shared__ __align__(16) unsigned short Bs[2][128 * 32];

  const int tid = threadIdx.x;
  const int lane = tid & 63;
  const int wv = tid >> 6;
  const int wm = wv >> 1, wn = wv & 1;
  const int n0 = blockIdx.x * 128;
  const int m0 = blockIdx.y * 128;
  const int split = blockIdx.z;
  const int r = lane & 15, g = lane >> 4;

  // staging: thread handles rows row0, row0+64, 16B chunk chk (swizzled slot)
  const int row0 = tid >> 2;
  const int row1 = row0 + 64;
  const int chk = tid & 3;
  const int lw0 = row0 * 32 + (((chk + ((row0 >> 1) & 3)) & 3) * 8);
  const int lw1 = row1 * 32 + (((chk + ((row1 >> 1) & 3)) & 3) * 8);

  int bb0, bho0, bwo0, bb1, bho1, bwo1;
  {
    int rn0 = n0 + row0, rn1 = n0 + row1;
    bb0 = rn0 >> LHW; bb1 = rn1 >> LHW;
    int re0 = rn0 & (HOWO - 1), re1 = rn1 & (HOWO - 1);
    bho0 = re0 >> LWO; bho1 = re1 >> LWO;
    bwo0 = re0 & (WO - 1); bwo1 = re1 & (WO - 1);
  }

  const int tap0 = split * TPS;
  int tapI = tap0, ccI = 0;              // issue pointer
  size_t boff0, boff1; bool bok0, bok1;
  auto tap_geom = [&](int t) {
    int kh = t >> 2, kw = t & 3;
    {
      int h = 2 * bho0 - 1 + kh, w = 2 * bwo0 - 1 + kw;
      bool hv = (unsigned)h < (unsigned)HI, wvv = (unsigned)w < (unsigned)WI;
      bok0 = hv && wvv;
      boff0 = (((size_t)bb0 * HI + (hv ? h : 0)) * WI + (wvv ? w : 0)) * (size_t)CSTOR;
    }
    {
      int h = 2 * bho1 - 1 + kh, w = 2 * bwo1 - 1 + kw;
      bool hv = (unsigned)h < (unsigned)HI, wvv = (unsigned)w < (unsigned)WI;
      bok1 = hv && wvv;
      boff1 = (((size_t)bb1 * HI + (hv ? h : 0)) * WI + (wvv ? w : 0)) * (size_t)CSTOR;
    }
  };
  tap_geom(tapI);

  auto issue = [&](uint4& a0r, uint4& a1r, uint4& b0r, uint4& b1r) {
    const int kbase = tapI * CINP + ccI * 32 + chk * 8;
    a0r = *reinterpret_cast<const uint4*>(Wt + (size_t)(m0 + row0) * KTOT + kbase);
    a1r = *reinterpret_cast<const uint4*>(Wt + (size_t)(m0 + row1) * KTOT + kbase);
    int ci = ccI * 32 + chk * 8;
    bool ok0 = bok0, ok1 = bok1;
    int cic = ci;
    if constexpr (CSTOR < CINP) {
      if (ci >= CSTOR) { ok0 = false; ok1 = false; cic = 0; }
    }
    uint4 z = make_uint4(0u, 0u, 0u, 0u);
    uint4 v0 = *reinterpret_cast<const uint4*>(X + boff0 + cic);
    uint4 v1 = *reinterpret_cast<const uint4*>(X + boff1 + cic);
    b0r = ok0 ? v0 : z;
    b1r = ok1 ? v1 : z;
  };
  auto advance = [&]() {
    ccI++;
    if (ccI == CPT) { ccI = 0; tapI++; if (tapI < tap0 + TPS) tap_geom(tapI); }
  };

  uint4 avA0, avA1, bvA0, bvA1;
  uint4 avB0, avB1, bvB0, bvB1;
  issue(avA0, avA1, bvA0, bvA1); advance();
  issue(avB0, avB1, bvB0, bvB1); advance();

  f32x4 acc[4][4] = {};

#define CONV_PHASE(BUF, AV0, AV1, BV0, BV1, HASNEXT)                                    \
  *reinterpret_cast<uint4*>(&As[BUF][lw0]) = AV0;                                       \
  *reinterpret_cast<uint4*>(&As[BUF][lw1]) = AV1;                                       \
  *reinterpret_cast<uint4*>(&Bs[BUF][lw0]) = BV0;                                       \
  *reinterpret_cast<uint4*>(&Bs[BUF][lw1]) = BV1;                                       \
  __syncthreads();                                                                      \
  if (HASNEXT) { issue(AV0, AV1, BV0, BV1); advance(); }                                \
  {                                                                                     \
    bf16x8 af[4], bf[4];                                                                \
    _Pragma("unroll")                                                                   \
    for (int mi = 0; mi < 4; ++mi) {                                                    \
      int rw = wm * 64 + mi * 16 + r;                                                   \
      af[mi] = *reinterpret_cast<const bf16x8*>(                                        \
          &As[BUF][rw * 32 + (((g + ((rw >> 1) & 3)) & 3) * 8)]);                       \
    }                                                                                   \
    _Pragma("unroll")                                                                   \
    for (int ni = 0; ni < 4; ++ni) {                                                    \
      int rw = wn * 64 + ni * 16 + r;                                                   \
      bf[ni] = *reinterpret_cast<const bf16x8*>(                                        \
          &Bs[BUF][rw * 32 + (((g + ((rw >> 1) & 3)) & 3) * 8)]);                       \
    }                                                                                   \
    _Pragma("unroll")                                                                   \
    for (int mi = 0; mi < 4; ++mi)                                                      \
      _Pragma("unroll")                                                                 \
      for (int ni = 0; ni < 4; ++ni)                                                    \
        acc[mi][ni] = __builtin_amdgcn_mfma_f32_16x16x32_bf16(af[mi], bf[ni],           \
                                                              acc[mi][ni], 0, 0, 0);    \
  }

  for (int ii = 0; ii < NIT / 2; ++ii) {
    CONV_PHASE(0, avA0, avA1, bvA0, bvA1, (2 * ii + 2 < NIT))
    CONV_PHASE(1, avB0, avB1, bvB0, bvB1, (2 * ii + 3 < NIT))
  }
#undef CONV_PHASE

  // epilogue: C frag mapping col(n)=lane&15=r, row(m)=g*4+q
#pragma unroll
  for (int ni = 0; ni < 4; ++ni) {
    int n = n0 + wn * 64 + ni * 16 + r;
    int b = n >> LHW;
    int rem = n & (HOWO - 1);
    size_t obase = ((size_t)b * HOWO + rem) * COUT;
#pragma unroll
    for (int mi = 0; mi < 4; ++mi) {
      int mb = m0 + wm * 64 + mi * 16 + g * 4;
      f32x4 a = acc[mi][ni];
      if constexpr (FUSED) {
        float v0 = a[0] + bias[mb + 0]; v0 = v0 > 0.f ? v0 : 0.2f * v0;
        float v1 = a[1] + bias[mb + 1]; v1 = v1 > 0.f ? v1 : 0.2f * v1;
        float v2 = a[2] + bias[mb + 2]; v2 = v2 > 0.f ? v2 : 0.2f * v2;
        float v3 = a[3] + bias[mb + 3]; v3 = v3 > 0.f ? v3 : 0.2f * v3;
        ushort4 o;
        o.x = f2bf(v0); o.y = f2bf(v1); o.z = f2bf(v2); o.w = f2bf(v3);
        *reinterpret_cast<ushort4*>(&Y[obase + mb]) = o;
      } else {
        *reinterpret_cast<float4*>(&P[split * PSTRIDE + obase + mb]) =
            make_float4(a[0], a[1], a[2], a[3]);
      }
    }
  }
}

// ---------------- NHWC split-reduce + instance norm + lrelu -> bf16 (single read) ----
// block: 8 channels x 32 hw-slices. grid (COUT/8, 8). values cached in registers.
template<int HOWO, int COUT, int NSPLIT>
__global__ __launch_bounds__(256)
void inorm_cl3_kernel(const float* __restrict__ P, unsigned short* __restrict__ Y) {
  constexpr int PER = HOWO / 32;
  constexpr size_t PSTRIDE = (size_t)8 * HOWO * COUT;
  const int b = blockIdx.y;
  const int cl = threadIdx.x & 7;
  const int c = blockIdx.x * 8 + cl;
  const int hw0 = threadIdx.x >> 3;   // 0..31
  const float* base = P + ((size_t)b * HOWO) * COUT + c;
  float v[PER];
  float s1 = 0.f, s2 = 0.f;
#pragma unroll
  for (int j = 0; j < PER; ++j) {
    int hw = hw0 + j * 32;
    float x = 0.f;
#pragma unroll
    for (int s = 0; s < NSPLIT; ++s) x += base[s * PSTRIDE + (size_t)hw * COUT];
    v[j] = x; s1 += x; s2 += x * x;
  }
  __shared__ float r1[32][9], r2[32][9];
  __shared__ float ms[8], rs[8];
  r1[hw0][cl] = s1; r2[hw0][cl] = s2;
  __syncthreads();
  if (threadIdx.x < 8) {
    float a1 = 0.f, a2 = 0.f;
#pragma unroll
    for (int i = 0; i < 32; ++i) { a1 += r1[i][threadIdx.x]; a2 += r2[i][threadIdx.x]; }
    float mean = a1 * (1.0f / HOWO);
    float var = a2 * (1.0f / HOWO) - mean * mean;
    ms[threadIdx.x] = mean;
    rs[threadIdx.x] = rsqrtf(var + 1e-5f);
  }
  __syncthreads();
  const float mean = ms[cl], rstd = rs[cl];
  unsigned short* yb = Y + ((size_t)b * HOWO) * COUT + c;
#pragma unroll
  for (int j = 0; j < PER; ++j) {
    int hw = hw0 + j * 32;
    float t = (v[j] - mean) * rstd;
    t = t > 0.f ? t : 0.2f * t;
    yb[(size_t)hw * COUT] = f2bf(t);
  }
}

// ---------------- NHWC avg pool 8x8: [8][64][1024] -> pooled [8][1024] fp32 --------
__global__ __launch_bounds__(256)
void pool_cl_kernel(const unsigned short* __restrict__ X, float* __restrict__ pooled) {
  const int b = blockIdx.x;
  const int c4 = threadIdx.x * 4;
  float4 acc = make_float4(0.f, 0.f, 0.f, 0.f);
  for (int hw = 0; hw < 64; ++hw) {
    ushort4 v = *reinterpret_cast<const ushort4*>(&X[((size_t)b * 64 + hw) * 1024 + c4]);
    acc.x += bf2f(v.x); acc.y += bf2f(v.y); acc.z += bf2f(v.z); acc.w += bf2f(v.w);
  }
  acc.x *= (1.0f / 64.0f); acc.y *= (1.0f / 64.0f);
  acc.z *= (1.0f / 64.0f); acc.w *= (1.0f / 64.0f);
  *reinterpret_cast<float4*>(&pooled[b * 1024 + c4]) = acc;
}

// ---------------- final linear ----------------
__global__ __launch_bounds__(64)
void fc_kernel(const float* __restrict__ pooled, const float* __restrict__ w4,
               const float* __restrict__ b4, float* __restrict__ out) {
  const int bo = blockIdx.x;
  const int b = bo >> 7, o = bo & 127;
  const int lane = threadIdx.x;
  float s = 0.f;
#pragma unroll
  for (int j = 0; j < 16; ++j) {
    int c = lane + j * 64;
    s += pooled[b * 1024 + c] * w4[o * 1024 + c];
  }
#pragma unroll
  for (int off = 32; off > 0; off >>= 1) s += __shfl_xor(s, off);
  if (lane == 0) out[bo] = s + b4[o];
}

extern "C" void kernel_launch(void* const* d_in, const int* in_sizes, int n_in,
                              void* d_out, int out_size, void* d_ws, size_t ws_size,
                              hipStream_t stream) {
  (void)in_sizes; (void)n_in; (void)out_size; (void)ws_size;
  const float* image = (const float*)d_in[0];
  const float* maskE = (const float*)d_in[1];
  const float* w0 = (const float*)d_in[2];
  const float* b0 = (const float*)d_in[3];
  const float* w1 = (const float*)d_in[4];
  const float* w2 = (const float*)d_in[6];
  const float* w3 = (const float*)d_in[8];
  const float* w4 = (const float*)d_in[10];
  const float* b4 = (const float*)d_in[11];
  float* out = (float*)d_out;

  char* ws = (char*)d_ws;
  size_t off = 0;
  auto alloc = [&](size_t bytes) -> void* {
    void* p = ws + off;
    off = (off + bytes + 255) & ~(size_t)255;
    return p;
  };

  // wbuf: one 32MB permuted-weight buffer, stream-ordered reuse.
  unsigned short* wbuf = (unsigned short*)alloc((size_t)1024 * 16384 * 2);
  // bufA: x0cl [8][128][128][144] bf16 (37.75MB), later fp32 split partials (<=33.6MB).
  char* bufA = (char*)alloc((size_t)8 * 128 * 128 * 144 * 2);
  // bufB: NHWC activations a0 (16.8MB) / a1 / a2 / a3, sequential reuse.
  char* bufB = (char*)alloc((size_t)8 * 4096 * 256 * 2);
  float2* col = (float2*)alloc((size_t)131072 * sizeof(float2));
  float2* tw = (float2*)alloc(128 * sizeof(float2));
  float* pooled = (float*)alloc(8192 * 4);

  unsigned short* x0 = (unsigned short*)bufA;
  float* part = (float*)bufA;
  unsigned short* a0 = (unsigned short*)bufB;
  unsigned short* a1 = (unsigned short*)bufB;
  unsigned short* a2 = (unsigned short*)bufB;
  unsigned short* a3 = (unsigned short*)bufB;

  // spectral map (channels-last)
  dft_kernel<<<1024, 128, 0, stream>>>(image, col, tw);
  sep_cl_kernel<<<1024, 256, 0, stream>>>(col, tw, maskE, x0);

  // conv0: 134(pad160)->256, fused bias+lrelu, full K
  cvtperm_kernel<134, 160><<<dim3(3, 256), 256, 0, stream>>>(w0, wbuf);
  conv_cl3_kernel<160, 144, 256, 128, 128, 64, 64, 1, true>
      <<<dim3(256, 2, 1), 256, 0, stream>>>(x0, wbuf, b0, a0, nullptr);

  // conv1: 256->512, split-K 2 (8 taps each)
  cvtperm_kernel<256, 256><<<dim3(4, 512), 256, 0, stream>>>(w1, wbuf);
  conv_cl3_kernel<256, 256, 512, 64, 64, 32, 32, 2, false>
      <<<dim3(64, 4, 2), 256, 0, stream>>>(a0, wbuf, nullptr, nullptr, part);
  inorm_cl3_kernel<1024, 512, 2><<<dim3(64, 8), 256, 0, stream>>>(part, a1);

  // conv2: 512->1024, split-K 4 (4 taps each)
  cvtperm_kernel<512, 512><<<dim3(8, 1024), 256, 0, stream>>>(w2, wbuf);
  conv_cl3_kernel<512, 512, 1024, 32, 32, 16, 16, 4, false>
      <<<dim3(16, 8, 4), 256, 0, stream>>>(a1, wbuf, nullptr, nullptr, part);
  inorm_cl3_kernel<256, 1024, 4><<<dim3(128, 8), 256, 0, stream>>>(part, a2);

  // conv3: 1024->1024, split-K 16 (1 tap each)
  cvtperm_kernel<1024, 1024><<<dim3(16, 1024), 256, 0, stream>>>(w3, wbuf);
  conv_cl3_kernel<1024, 1024, 1024, 16, 16, 8, 8, 16, false>
      <<<dim3(4, 8, 16), 256, 0, stream>>>(a2, wbuf, nullptr, nullptr, part);
  inorm_cl3_kernel<64, 1024, 16><<<dim3(128, 8), 256, 0, stream>>>(part, a3);

  // pool + fc
  pool_cl_kernel<<<8, 256, 0, stream>>>(a3, pooled);
  fc_kernel<<<1024, 64, 0, stream>>>(pooled, w4, b4, out);
}